// Round 3
// baseline (186.172 us; speedup 1.0000x reference)
//
#include <hip/hip_runtime.h>
#include <stdint.h>

#define N 2048
#define TILE 128
#define BK 64
#define KH 16            // K-steps per half-pipeline (2 halves x 16 = 32 total)
#define LDSW 72          // u16 row stride: 144 B rows; 4(lr+q) bank spread = conflict-free b128
#define RSTR 17          // f32 row stride for the K-half exchange slots
#define NN ((size_t)N * (size_t)N)

typedef unsigned short u16;
typedef __bf16 bf16x8 __attribute__((ext_vector_type(8)));
typedef unsigned short ushortx8 __attribute__((ext_vector_type(8)));
typedef float floatx4 __attribute__((ext_vector_type(4)));

static __device__ __forceinline__ u16 f2bf(float f) {
  unsigned int u = __builtin_bit_cast(unsigned int, f);
  return (u16)((u + 0x7fffu + ((u >> 16) & 1u)) >> 16);  // RNE, finite inputs
}
static __device__ __forceinline__ float bf2f(u16 h) {
  unsigned int u = ((unsigned int)h) << 16;
  return __builtin_bit_cast(float, u);
}

// ---------------------------------------------------------------------------
// cast + transpose: Ab[r][c] = bf16(A[r][c]); Abt[c][r] = bf16(A[r][c])
// ---------------------------------------------------------------------------
__global__ void cast_tr(const float* __restrict__ A, u16* __restrict__ Ab,
                        u16* __restrict__ Abt) {
  __shared__ float tile[32][33];
  const int tx = threadIdx.x, ty = threadIdx.y;
  const int c = blockIdx.x * 32 + tx;
#pragma unroll
  for (int i = 0; i < 4; i++) {
    const int r = blockIdx.y * 32 + ty + i * 8;
    const float v = A[(size_t)r * N + c];
    Ab[(size_t)r * N + c] = f2bf(v);
    tile[ty + i * 8][tx] = v;
  }
  __syncthreads();
  const int r2 = blockIdx.y * 32 + tx;
#pragma unroll
  for (int i = 0; i < 4; i++) {
    const int c2 = blockIdx.x * 32 + ty + i * 8;
    Abt[(size_t)c2 * N + r2] = f2bf(tile[tx][ty + i * 8]);
  }
}

// ---------------------------------------------------------------------------
// GEMM core: C = L[128 x N] * R[N x 128] (Rt stored [n][k]).
// 1024 threads = 16 waves = 4 waves/SIMD (round 2 had 2/SIMD at 1 block/CU —
// concurrency-starved: ~3072 cyc/step observed vs ~1000 cyc LDS floor).
// In-block split-K: half h = w>>3 processes K in [h*1024, h*1024+1024) in its
// own double-buffered pipeline (separate LDS buffers); halves share the
// block barrier in lockstep. Wave sub = w&7 owns a 64x32 output subtile ->
// acc[4][2] = 32 VGPRs (round-1's acc[4][4] spilled; not repeated).
// One barrier per step (proven rounds 1-2). Depth-2 register prefetch.
// Epilogue: K-half pair reduction through LDS aliasing the dead staging
// buffers; after it, acc[mt][h] holds the final 16-col block this wave keeps
// (acc[mt][1-h] is garbage — callers must only store nt==h).
// ---------------------------------------------------------------------------
__device__ __forceinline__ void gemm_core(const u16* __restrict__ L,
                                          const u16* __restrict__ Rt,
                                          floatx4 acc[4][2]) {
  __shared__ __align__(16) u16 As[2][2][TILE * LDSW];  // [half][buf] 73,728 B
  __shared__ __align__(16) u16 Bs[2][2][TILE * LDSW];  // [half][buf] 73,728 B

  const int t = threadIdx.x;             // 0..1023
  const int h = t >> 9;                  // K-half
  const int tl = t & 511;
  const int row0 = blockIdx.y * TILE;
  const int col0 = blockIdx.x * TILE;

  // staging map (per half): thread tl covers row tl>>2, 32B chunk tl&3
  const int srow = tl >> 2;
  const int sc = (tl & 3) * 16;          // u16 offset
  const u16* gA = L + (size_t)(row0 + srow) * N + h * (KH * BK) + sc;
  const u16* gB = Rt + (size_t)(col0 + srow) * N + h * (KH * BK) + sc;
  const int woff = srow * LDSW + sc;

  const int lane = t & 63;
  const int w = t >> 6;                  // 0..15
  const int sub = w & 7;
  const int wr = (sub >> 2) * 64;
  const int wc = (sub & 3) * 32;
  const int lr = lane & 15;
  const int q = lane >> 4;
  const int abase = (wr + lr) * LDSW + q * 8;
  const int bbase = (wc + lr) * LDSW + q * 8;

#pragma unroll
  for (int i = 0; i < 4; i++)
#pragma unroll
    for (int j = 0; j < 2; j++) acc[i][j] = (floatx4){0.f, 0.f, 0.f, 0.f};

  ushortx8 sA[2][2], sB[2][2];           // [slot = tile&1][16B chunk]
  // prologue: tiles 0 and 1 of this half into registers; publish tile 0
  sA[0][0] = *(const ushortx8*)(gA);
  sA[0][1] = *(const ushortx8*)(gA + 8);
  sB[0][0] = *(const ushortx8*)(gB);
  sB[0][1] = *(const ushortx8*)(gB + 8);
  sA[1][0] = *(const ushortx8*)(gA + BK);
  sA[1][1] = *(const ushortx8*)(gA + BK + 8);
  sB[1][0] = *(const ushortx8*)(gB + BK);
  sB[1][1] = *(const ushortx8*)(gB + BK + 8);
  *(ushortx8*)&As[h][0][woff] = sA[0][0];
  *(ushortx8*)&As[h][0][woff + 8] = sA[0][1];
  *(ushortx8*)&Bs[h][0][woff] = sB[0][0];
  *(ushortx8*)&Bs[h][0][woff + 8] = sB[0][1];
  __syncthreads();

#define GSTEP(i, cur, nxt)                                                    \
  {                                                                           \
    if ((i) + 2 < KH) {                                                       \
      sA[cur][0] = *(const ushortx8*)(gA + ((i) + 2) * BK);                   \
      sA[cur][1] = *(const ushortx8*)(gA + ((i) + 2) * BK + 8);               \
      sB[cur][0] = *(const ushortx8*)(gB + ((i) + 2) * BK);                   \
      sB[cur][1] = *(const ushortx8*)(gB + ((i) + 2) * BK + 8);               \
    }                                                                         \
    _Pragma("unroll") for (int kk = 0; kk < 2; kk++) {                        \
      bf16x8 af[4], bfr[2];                                                   \
      _Pragma("unroll") for (int mt = 0; mt < 4; mt++) af[mt] =               \
          __builtin_bit_cast(bf16x8,                                          \
              *(const ushortx8*)&As[h][cur][abase + kk * 32 + mt * 16 * LDSW]); \
      _Pragma("unroll") for (int nt = 0; nt < 2; nt++) bfr[nt] =              \
          __builtin_bit_cast(bf16x8,                                          \
              *(const ushortx8*)&Bs[h][cur][bbase + kk * 32 + nt * 16 * LDSW]); \
      _Pragma("unroll") for (int mt = 0; mt < 4; mt++)                        \
          _Pragma("unroll") for (int nt = 0; nt < 2; nt++) acc[mt][nt] =      \
              __builtin_amdgcn_mfma_f32_16x16x32_bf16(af[mt], bfr[nt],        \
                                                      acc[mt][nt], 0, 0, 0);  \
    }                                                                         \
    if ((i) + 1 < KH) {                                                       \
      *(ushortx8*)&As[h][nxt][woff] = sA[nxt][0];                             \
      *(ushortx8*)&As[h][nxt][woff + 8] = sA[nxt][1];                         \
      *(ushortx8*)&Bs[h][nxt][woff] = sB[nxt][0];                             \
      *(ushortx8*)&Bs[h][nxt][woff + 8] = sB[nxt][1];                         \
    }                                                                         \
    __syncthreads();                                                          \
  }

  for (int io = 0; io < KH; io += 2) {
    GSTEP(io, 0, 1)
    GSTEP(io + 1, 1, 0)
  }
#undef GSTEP

  // K-half pair reduction. Aliases As (dead after the final barrier; every
  // wave's LDS reads were lgkm-drained before it reached that barrier).
  // Wave (sub,h) ships the nt=1-h column block to slot (sub,1-h), then adds
  // the partner's shipment from slot (sub,h) into its kept block nt=h.
  // 16 slots x 64x17 f32 = 69,632 B <= sizeof(As).
  float* red = (float*)&As[0][0][0];
  const int oh = 1 - h;
  const int rship = (sub * 2 + oh) * (64 * RSTR);
  const int rkeep = (sub * 2 + h) * (64 * RSTR);
#pragma unroll
  for (int mt = 0; mt < 4; mt++)
#pragma unroll
    for (int r = 0; r < 4; r++)
      red[rship + (mt * 16 + q * 4 + r) * RSTR + lr] = acc[mt][oh][r];
  __syncthreads();
#pragma unroll
  for (int mt = 0; mt < 4; mt++)
#pragma unroll
    for (int r = 0; r < 4; r++)
      acc[mt][h][r] += red[rkeep + (mt * 16 + q * 4 + r) * RSTR + lr];
}

// GEMM1: Mb = bf16(A @ A)
__global__ __launch_bounds__(1024, 4) void gemm_aa(const u16* __restrict__ Ab,
                                                   const u16* __restrict__ Abt,
                                                   u16* __restrict__ Mb) {
  floatx4 acc[4][2];
  gemm_core(Ab, Abt, acc);
  const int t = threadIdx.x;
  const int lane = t & 63, w = t >> 6;
  const int sub = w & 7, h = w >> 3;
  const int wr = (sub >> 2) * 64, wc = (sub & 3) * 32;
  const int lr = lane & 15, q = lane >> 4;
  const int row0 = blockIdx.y * TILE, col0 = blockIdx.x * TILE;
  const int cc = col0 + wc + h * 16 + lr;  // kept 16-col block
#pragma unroll
  for (int mt = 0; mt < 4; mt++)
#pragma unroll
    for (int r = 0; r < 4; r++) {
      const int rr = row0 + wr + mt * 16 + q * 4 + r;
      Mb[(size_t)rr * N + cc] = f2bf(acc[mt][h][r]);
    }
}

// rdeg[i] = 1 / (4*rowsum(M)_i + 1)   (with reference's <=1e-10 guard)
__global__ void rowsum_k(const u16* __restrict__ Mb, float* __restrict__ rdeg) {
  const int row = blockIdx.x;
  const int t = threadIdx.x;
  const ushortx8 v = *((const ushortx8*)(Mb + (size_t)row * N) + t);
  float s = 0.f;
#pragma unroll
  for (int j = 0; j < 8; j++) s += bf2f(v[j]);
#pragma unroll
  for (int off = 32; off > 0; off >>= 1) s += __shfl_down(s, off, 64);
  __shared__ float ws[4];
  if ((t & 63) == 0) ws[t >> 6] = s;
  __syncthreads();
  if (t == 0) {
    float d = 4.f * (ws[0] + ws[1] + ws[2] + ws[3]) + 1.f;
    if (d <= 1e-10f) d = 1.f;
    rdeg[row] = 1.f / d;
  }
}

// GEMM2 + fused norm epilogue: out = (8*(M@A) + 2*A) * rdeg[row]
__global__ __launch_bounds__(1024, 4) void gemm_ma(const u16* __restrict__ Mb,
                                                   const u16* __restrict__ Abt,
                                                   const float* __restrict__ A,
                                                   const float* __restrict__ rdeg,
                                                   float* __restrict__ out) {
  floatx4 acc[4][2];
  gemm_core(Mb, Abt, acc);
  const int t = threadIdx.x;
  const int lane = t & 63, w = t >> 6;
  const int sub = w & 7, h = w >> 3;
  const int wr = (sub >> 2) * 64, wc = (sub & 3) * 32;
  const int lr = lane & 15, q = lane >> 4;
  const int row0 = blockIdx.y * TILE, col0 = blockIdx.x * TILE;
  const int cc = col0 + wc + h * 16 + lr;  // kept 16-col block
#pragma unroll
  for (int mt = 0; mt < 4; mt++)
#pragma unroll
    for (int r = 0; r < 4; r++) {
      const int rr = row0 + wr + mt * 16 + q * 4 + r;
      out[(size_t)rr * N + cc] =
          (8.f * acc[mt][h][r] + 2.f * A[(size_t)rr * N + cc]) * rdeg[rr];
    }
}

extern "C" void kernel_launch(void* const* d_in, const int* in_sizes, int n_in,
                              void* d_out, int out_size, void* d_ws, size_t ws_size,
                              hipStream_t stream) {
  const float* A = (const float*)d_in[0];
  // GTConv weights (d_in[1..3]) are irrelevant: softmax over a singleton axis
  // is identically 1, so each conv output is exactly 2*A.
  float* out = (float*)d_out;
  char* ws = (char*)d_ws;
  u16* Ab = (u16*)ws;                          // 8 MB bf16 A row-major
  u16* Abt = (u16*)(ws + NN * 2);              // 8 MB bf16 A transposed
  u16* Mb = (u16*)(ws + NN * 4);               // 8 MB bf16 M = A@A
  float* rdeg = (float*)(ws + NN * 6);         // 8 KB reciprocal degrees

  cast_tr<<<dim3(N / 32, N / 32), dim3(32, 8), 0, stream>>>(A, Ab, Abt);
  gemm_aa<<<dim3(N / TILE, N / TILE), 1024, 0, stream>>>(Ab, Abt, Mb);
  rowsum_k<<<N, 256, 0, stream>>>(Mb, rdeg);
  gemm_ma<<<dim3(N / TILE, N / TILE), 1024, 0, stream>>>(Mb, Abt, A, rdeg, out);
}

// Round 4
// 128.428 us; speedup vs baseline: 1.4496x; 1.4496x over previous
//
#include <hip/hip_runtime.h>
#include <stdint.h>

#define N 2048
#define TILE 128
#define BK 64
#define KH 16            // K-steps per half-pipeline (2 halves x 16 = 32 total)
#define LDSW 72          // u16 row stride: 144 B rows; 16B-aligned b128
#define RSTR 17          // f32 row stride for the K-half exchange slots
#define NN ((size_t)N * (size_t)N)

typedef unsigned short u16;
typedef __bf16 bf16x8 __attribute__((ext_vector_type(8)));
typedef unsigned short ushortx8 __attribute__((ext_vector_type(8)));
typedef float floatx4 __attribute__((ext_vector_type(4)));

static __device__ __forceinline__ u16 f2bf(float f) {
  unsigned int u = __builtin_bit_cast(unsigned int, f);
  return (u16)((u + 0x7fffu + ((u >> 16) & 1u)) >> 16);  // RNE, finite inputs
}
static __device__ __forceinline__ float bf2f(u16 h) {
  unsigned int u = ((unsigned int)h) << 16;
  return __builtin_bit_cast(float, u);
}

// ---------------------------------------------------------------------------
// cast + transpose: Ab[r][c] = bf16(A[r][c]); Abt[c][r] = bf16(A[r][c])
// ---------------------------------------------------------------------------
__global__ void cast_tr(const float* __restrict__ A, u16* __restrict__ Ab,
                        u16* __restrict__ Abt) {
  __shared__ float tile[32][33];
  const int tx = threadIdx.x, ty = threadIdx.y;
  const int c = blockIdx.x * 32 + tx;
#pragma unroll
  for (int i = 0; i < 4; i++) {
    const int r = blockIdx.y * 32 + ty + i * 8;
    const float v = A[(size_t)r * N + c];
    Ab[(size_t)r * N + c] = f2bf(v);
    tile[ty + i * 8][tx] = v;
  }
  __syncthreads();
  const int r2 = blockIdx.y * 32 + tx;
#pragma unroll
  for (int i = 0; i < 4; i++) {
    const int c2 = blockIdx.x * 32 + ty + i * 8;
    Abt[(size_t)c2 * N + r2] = f2bf(tile[tx][ty + i * 8]);
  }
}

// ---------------------------------------------------------------------------
// GEMM core: C = L[128 x N] * R[N x 128] (Rt stored [n][k]).
// 1024 threads = 16 waves = 4 waves/SIMD (round 2's 2/SIMD at 1 block/CU was
// bubble-starved). In-block split-K: half h = w>>3 processes K in
// [h*1024, h*1024+1024) in its own double-buffered pipeline; halves share the
// block barrier in lockstep. Wave sub = w&7 owns a 64x32 output subtile ->
// acc[4][2] = 32 regs. One barrier per step. Depth-2 register prefetch.
//
// RULE #20 (learn_hip m214 r286): NEVER index a register array with a
// runtime value (rounds 1 & 3 both did acc[..][h] -> whole acc demoted to
// scratch: VGPR_Count=64, MfmaUtil 10%, GB-scale scratch traffic). All
// register-array indices below are compile-time; runtime-h selection is done
// on VALUES via ternary (v_cndmask), and the K-half exchange result is
// returned in a static-indexed res[4][4].
// ---------------------------------------------------------------------------
__device__ __forceinline__ void gemm_core(const u16* __restrict__ L,
                                          const u16* __restrict__ Rt,
                                          float res[4][4]) {
  __shared__ __align__(16) u16 As[2][2][TILE * LDSW];  // [half][buf] 73,728 B
  __shared__ __align__(16) u16 Bs[2][2][TILE * LDSW];  // [half][buf] 73,728 B

  const int t = threadIdx.x;             // 0..1023
  const int h = t >> 9;                  // K-half
  const int tl = t & 511;
  const int row0 = blockIdx.y * TILE;
  const int col0 = blockIdx.x * TILE;

  // staging map (per half): thread tl covers row tl>>2, 32B chunk tl&3
  const int srow = tl >> 2;
  const int sc = (tl & 3) * 16;          // u16 offset
  const u16* gA = L + (size_t)(row0 + srow) * N + h * (KH * BK) + sc;
  const u16* gB = Rt + (size_t)(col0 + srow) * N + h * (KH * BK) + sc;
  const int woff = srow * LDSW + sc;

  const int lane = t & 63;
  const int w = t >> 6;                  // 0..15
  const int sub = w & 7;
  const int wr = (sub >> 2) * 64;
  const int wc = (sub & 3) * 32;
  const int lr = lane & 15;
  const int q = lane >> 4;
  const int abase = (wr + lr) * LDSW + q * 8;
  const int bbase = (wc + lr) * LDSW + q * 8;

  floatx4 acc[4][2];
#pragma unroll
  for (int i = 0; i < 4; i++)
#pragma unroll
    for (int j = 0; j < 2; j++) acc[i][j] = (floatx4){0.f, 0.f, 0.f, 0.f};

  ushortx8 sA[2][2], sB[2][2];           // [slot = tile&1][16B chunk]
  // prologue: tiles 0 and 1 of this half into registers; publish tile 0
  sA[0][0] = *(const ushortx8*)(gA);
  sA[0][1] = *(const ushortx8*)(gA + 8);
  sB[0][0] = *(const ushortx8*)(gB);
  sB[0][1] = *(const ushortx8*)(gB + 8);
  sA[1][0] = *(const ushortx8*)(gA + BK);
  sA[1][1] = *(const ushortx8*)(gA + BK + 8);
  sB[1][0] = *(const ushortx8*)(gB + BK);
  sB[1][1] = *(const ushortx8*)(gB + BK + 8);
  *(ushortx8*)&As[h][0][woff] = sA[0][0];
  *(ushortx8*)&As[h][0][woff + 8] = sA[0][1];
  *(ushortx8*)&Bs[h][0][woff] = sB[0][0];
  *(ushortx8*)&Bs[h][0][woff + 8] = sB[0][1];
  __syncthreads();

#define GSTEP(i, cur, nxt)                                                    \
  {                                                                           \
    if ((i) + 2 < KH) {                                                       \
      sA[cur][0] = *(const ushortx8*)(gA + ((i) + 2) * BK);                   \
      sA[cur][1] = *(const ushortx8*)(gA + ((i) + 2) * BK + 8);               \
      sB[cur][0] = *(const ushortx8*)(gB + ((i) + 2) * BK);                   \
      sB[cur][1] = *(const ushortx8*)(gB + ((i) + 2) * BK + 8);               \
    }                                                                         \
    _Pragma("unroll") for (int kk = 0; kk < 2; kk++) {                        \
      bf16x8 af[4], bfr[2];                                                   \
      _Pragma("unroll") for (int mt = 0; mt < 4; mt++) af[mt] =               \
          __builtin_bit_cast(bf16x8,                                          \
              *(const ushortx8*)&As[h][cur][abase + kk * 32 + mt * 16 * LDSW]); \
      _Pragma("unroll") for (int nt = 0; nt < 2; nt++) bfr[nt] =              \
          __builtin_bit_cast(bf16x8,                                          \
              *(const ushortx8*)&Bs[h][cur][bbase + kk * 32 + nt * 16 * LDSW]); \
      _Pragma("unroll") for (int mt = 0; mt < 4; mt++)                        \
          _Pragma("unroll") for (int nt = 0; nt < 2; nt++) acc[mt][nt] =      \
              __builtin_amdgcn_mfma_f32_16x16x32_bf16(af[mt], bfr[nt],        \
                                                      acc[mt][nt], 0, 0, 0);  \
    }                                                                         \
    if ((i) + 1 < KH) {                                                       \
      *(ushortx8*)&As[h][nxt][woff] = sA[nxt][0];                             \
      *(ushortx8*)&As[h][nxt][woff + 8] = sA[nxt][1];                         \
      *(ushortx8*)&Bs[h][nxt][woff] = sB[nxt][0];                             \
      *(ushortx8*)&Bs[h][nxt][woff + 8] = sB[nxt][1];                         \
    }                                                                         \
    __syncthreads();                                                          \
  }

  for (int io = 0; io < KH; io += 2) {
    GSTEP(io, 0, 1)
    GSTEP(io + 1, 1, 0)
  }
#undef GSTEP

  // K-half pair reduction. Aliases As (dead after the final barrier; every
  // wave's LDS reads were lgkm-drained before it reached that barrier).
  // Wave (sub,h) ships its nt=(1-h) column block to slot (sub,1-h), then
  // reads the partner's shipment from slot (sub,h) and adds it to its kept
  // block nt=h. 16 slots x 64x17 f32 = 69,632 B <= sizeof(As).
  // ALL acc accesses use static indices; h selects values only.
  float* red = (float*)&As[0][0][0];
  const int oh = 1 - h;
  const int rship = (sub * 2 + oh) * (64 * RSTR);
  const int rkeep = (sub * 2 + h) * (64 * RSTR);
#pragma unroll
  for (int mt = 0; mt < 4; mt++)
#pragma unroll
    for (int r = 0; r < 4; r++) {
      const float vship = h ? acc[mt][0][r] : acc[mt][1][r];
      red[rship + (mt * 16 + q * 4 + r) * RSTR + lr] = vship;
    }
  __syncthreads();
#pragma unroll
  for (int mt = 0; mt < 4; mt++)
#pragma unroll
    for (int r = 0; r < 4; r++) {
      const float vkeep = h ? acc[mt][1][r] : acc[mt][0][r];
      res[mt][r] = vkeep + red[rkeep + (mt * 16 + q * 4 + r) * RSTR + lr];
    }
}

// GEMM1: Mb = bf16(A @ A)
__global__ __launch_bounds__(1024, 4) void gemm_aa(const u16* __restrict__ Ab,
                                                   const u16* __restrict__ Abt,
                                                   u16* __restrict__ Mb) {
  float res[4][4];
  gemm_core(Ab, Abt, res);
  const int t = threadIdx.x;
  const int lane = t & 63, w = t >> 6;
  const int sub = w & 7, h = w >> 3;
  const int wr = (sub >> 2) * 64, wc = (sub & 3) * 32;
  const int lr = lane & 15, q = lane >> 4;
  const int row0 = blockIdx.y * TILE, col0 = blockIdx.x * TILE;
  const int cc = col0 + wc + h * 16 + lr;  // kept 16-col block
#pragma unroll
  for (int mt = 0; mt < 4; mt++)
#pragma unroll
    for (int r = 0; r < 4; r++) {
      const int rr = row0 + wr + mt * 16 + q * 4 + r;
      Mb[(size_t)rr * N + cc] = f2bf(res[mt][r]);
    }
}

// rdeg[i] = 1 / (4*rowsum(M)_i + 1)   (with reference's <=1e-10 guard)
__global__ void rowsum_k(const u16* __restrict__ Mb, float* __restrict__ rdeg) {
  const int row = blockIdx.x;
  const int t = threadIdx.x;
  const ushortx8 v = *((const ushortx8*)(Mb + (size_t)row * N) + t);
  float s = 0.f;
#pragma unroll
  for (int j = 0; j < 8; j++) s += bf2f(v[j]);
#pragma unroll
  for (int off = 32; off > 0; off >>= 1) s += __shfl_down(s, off, 64);
  __shared__ float ws[4];
  if ((t & 63) == 0) ws[t >> 6] = s;
  __syncthreads();
  if (t == 0) {
    float d = 4.f * (ws[0] + ws[1] + ws[2] + ws[3]) + 1.f;
    if (d <= 1e-10f) d = 1.f;
    rdeg[row] = 1.f / d;
  }
}

// GEMM2 + fused norm epilogue: out = (8*(M@A) + 2*A) * rdeg[row]
__global__ __launch_bounds__(1024, 4) void gemm_ma(const u16* __restrict__ Mb,
                                                   const u16* __restrict__ Abt,
                                                   const float* __restrict__ A,
                                                   const float* __restrict__ rdeg,
                                                   float* __restrict__ out) {
  float res[4][4];
  gemm_core(Mb, Abt, res);
  const int t = threadIdx.x;
  const int lane = t & 63, w = t >> 6;
  const int sub = w & 7, h = w >> 3;
  const int wr = (sub >> 2) * 64, wc = (sub & 3) * 32;
  const int lr = lane & 15, q = lane >> 4;
  const int row0 = blockIdx.y * TILE, col0 = blockIdx.x * TILE;
  const int cc = col0 + wc + h * 16 + lr;  // kept 16-col block
#pragma unroll
  for (int mt = 0; mt < 4; mt++)
#pragma unroll
    for (int r = 0; r < 4; r++) {
      const int rr = row0 + wr + mt * 16 + q * 4 + r;
      out[(size_t)rr * N + cc] =
          (8.f * res[mt][r] + 2.f * A[(size_t)rr * N + cc]) * rdeg[rr];
    }
}

extern "C" void kernel_launch(void* const* d_in, const int* in_sizes, int n_in,
                              void* d_out, int out_size, void* d_ws, size_t ws_size,
                              hipStream_t stream) {
  const float* A = (const float*)d_in[0];
  // GTConv weights (d_in[1..3]) are irrelevant: softmax over a singleton axis
  // is identically 1, so each conv output is exactly 2*A.
  float* out = (float*)d_out;
  char* ws = (char*)d_ws;
  u16* Ab = (u16*)ws;                          // 8 MB bf16 A row-major
  u16* Abt = (u16*)(ws + NN * 2);              // 8 MB bf16 A transposed
  u16* Mb = (u16*)(ws + NN * 4);               // 8 MB bf16 M = A@A
  float* rdeg = (float*)(ws + NN * 6);         // 8 KB reciprocal degrees

  cast_tr<<<dim3(N / 32, N / 32), dim3(32, 8), 0, stream>>>(A, Ab, Abt);
  gemm_aa<<<dim3(N / TILE, N / TILE), 1024, 0, stream>>>(Ab, Abt, Mb);
  rowsum_k<<<N, 256, 0, stream>>>(Mb, rdeg);
  gemm_ma<<<dim3(N / TILE, N / TILE), 1024, 0, stream>>>(Mb, Abt, A, rdeg, out);
}